// Round 1
// 714.889 us; speedup vs baseline: 1.7352x; 1.7352x over previous
//
#include <hip/hip_runtime.h>
#include <math.h>
#include <string.h>

#define B_   2048
#define TT   128
#define TA   256
#define TV   256
#define CT   300
#define CA   74
#define CV   35
#define D    64
#define E_   4
#define R_   8
#define H_   4
#define L_   4
#define NC   7
#define POOLW 416  // 409 padded to 16B multiple

// All INPUTS are float32 (reference dtype; confirmed: bf16 reads gave NaN in R1).
// OUTPUT buffer is float32. Params = 50 const pointers in setup_inputs() order, then out/ws views.
struct Params {
  const float *text, *audio, *video;
  const float *text_w, *text_b, *text_ln_g, *text_ln_b;
  const float *audio_w, *audio_b, *audio_ln_g, *audio_ln_b;
  const float *video_w, *video_b, *video_ln_g, *video_ln_b;
  const float *latent;
  const float *wq, *bq, *wk, *bk, *wv, *bv, *wo, *bo;
  const float *n1_g, *n1_b, *ffn_w1, *ffn_b1, *ffn_w2, *ffn_b2, *n2_g, *n2_b;
  const float *r_w1, *r_b1, *r_ln_g, *r_ln_b, *r_w2, *r_b2;
  const float *p1_w, *p1_b, *p2_w, *p2_b;
  const float *lora_down, *lora_up;
  const float *c_ln_g, *c_ln_b, *c_w1, *c_b1, *c_w2, *c_b2;
  float *out;
  const float *pool;   // [B_, POOLW] in d_ws
  const float *qbuf;   // [L_*D]     in d_ws
};

// sum across the 64 lanes of a wave (all lanes get the result)
__device__ __forceinline__ float wsum(float v) {
#pragma unroll
  for (int m = 32; m >= 1; m >>= 1) v += __shfl_xor(v, m, 64);
  return v;
}
// sum within each 16-lane group (all lanes of the group get the result)
__device__ __forceinline__ float hsum16(float v) {
#pragma unroll
  for (int m = 8; m >= 1; m >>= 1) v += __shfl_xor(v, m, 64);
  return v;
}
// compile-time reorder fence for wave-synchronous LDS produce->consume
#define WB() __builtin_amdgcn_wave_barrier()

// ================= Kernel A: streaming mean-pool (memory-bound) =================
// grid (B_, 3): y=0 text [128,300] f4-vectorized; y=1 audio [256,74] f2; y=2 video [256,35] scalar.
__global__ __launch_bounds__(256) void pool_kernel(
    const float* __restrict__ text, const float* __restrict__ audio,
    const float* __restrict__ video, const float* __restrict__ latent,
    const float* __restrict__ wq, const float* __restrict__ bq,
    float* __restrict__ pool, float* __restrict__ qbuf) {
  const int b = blockIdx.x;
  const int m = blockIdx.y;
  const int tid = threadIdx.x;
  __shared__ __align__(16) float sbuf[912];  // text: 225 float4 = 900 floats (max)

  if (m == 0) {
    // ---- text: 75 float4-cols x 3 row-groups = 225 threads; rows stride 1200B (16B aligned) ----
    const float* x = text + (size_t)b * (TT * CT);
    const int c4 = tid % 75, g = tid / 75;
    if (g < 3) {
      float4 acc = make_float4(0.f, 0.f, 0.f, 0.f);
      for (int t = g; t < TT; t += 3) {
        float4 v = *reinterpret_cast<const float4*>(x + t * CT + 4 * c4);
        acc.x += v.x; acc.y += v.y; acc.z += v.z; acc.w += v.w;
      }
      reinterpret_cast<float4*>(sbuf)[g * 75 + c4] = acc;
    }
    __syncthreads();
    if (tid < 75) {
      float4 a = reinterpret_cast<float4*>(sbuf)[tid];
      float4 bb = reinterpret_cast<float4*>(sbuf)[75 + tid];
      float4 c = reinterpret_cast<float4*>(sbuf)[150 + tid];
      float4 r;
      r.x = (a.x + bb.x + c.x) * (1.f / TT);
      r.y = (a.y + bb.y + c.y) * (1.f / TT);
      r.z = (a.z + bb.z + c.z) * (1.f / TT);
      r.w = (a.w + bb.w + c.w) * (1.f / TT);
      *reinterpret_cast<float4*>(pool + (size_t)b * POOLW + 4 * tid) = r;
    }
    // q = latent @ wq + bq is b-independent: compute once (block b==0)
    if (b == 0) {
      const int l = tid >> 6, j = tid & 63;
      float acc = bq[j];
      for (int i = 0; i < D; ++i) acc += latent[l * D + i] * wq[i * D + j];
      qbuf[l * D + j] = acc;
    }
  } else if (m == 1) {
    // ---- audio: 37 float2-cols x 6 row-groups = 222 threads; rows stride 296B (8B aligned) ----
    const float* x = audio + (size_t)b * (TA * CA);
    const int c2 = tid % 37, g = tid / 37;
    if (g < 6) {
      float2 acc = make_float2(0.f, 0.f);
      for (int t = g; t < TA; t += 6) {
        float2 v = *reinterpret_cast<const float2*>(x + t * CA + 2 * c2);
        acc.x += v.x; acc.y += v.y;
      }
      reinterpret_cast<float2*>(sbuf)[g * 37 + c2] = acc;
    }
    __syncthreads();
    if (tid < 37) {
      float2 r = make_float2(0.f, 0.f);
#pragma unroll
      for (int g2 = 0; g2 < 6; ++g2) {
        float2 v = reinterpret_cast<float2*>(sbuf)[g2 * 37 + tid];
        r.x += v.x; r.y += v.y;
      }
      r.x *= (1.f / TA); r.y *= (1.f / TA);
      *reinterpret_cast<float2*>(pool + (size_t)b * POOLW + CT + 2 * tid) = r;
    }
  } else {
    // ---- video: 35 cols x 7 row-groups = 245 threads; scalar (rows stride 140B) ----
    const float* x = video + (size_t)b * (TV * CV);
    const int c = tid % 35, g = tid / 35;
    if (g < 7) {
      float acc = 0.f;
      for (int t = g; t < TV; t += 7) acc += x[t * CV + c];
      sbuf[g * 35 + c] = acc;
    }
    __syncthreads();
    if (tid < 35) {
      float r = 0.f;
#pragma unroll
      for (int g2 = 0; g2 < 7; ++g2) r += sbuf[g2 * 35 + tid];
      pool[(size_t)b * POOLW + CT + CA + tid] = r * (1.f / TV);
    }
  }
}

// ================= Kernel B: head, one wave per sample (latency-optimized) =================
// 256 threads = 4 waves = 4 samples. All cross-lane comm is wave-local (shuffles or per-wave
// LDS slice); no __syncthreads in the main path -> 8 independent chains per CU.
__global__ __launch_bounds__(256) void head_kernel(Params p) {
  const int tid = threadIdx.x;
  const int lane = tid & 63;
  const int w = tid >> 6;
  const int b = blockIdx.x * 4 + w;

  __shared__ float s_q[L_ * D];            // block-shared (constant)
  __shared__ float s_pool[4][POOLW];       // per-wave slices below
  __shared__ float s_z[4][3 * D];
  __shared__ float s_k[4][3 * D];
  __shared__ float s_ao[4][L_ * D];
  __shared__ float s_lat1[4][L_ * D];
  __shared__ float s_h1[4][L_ * 256];
  __shared__ float s_f[4][D];
  __shared__ float s_down[4][E_ * R_];
  __shared__ float s_cl[4][D];

  s_q[tid] = p.qbuf[tid];  // 256 == L_*D
  for (int i = lane; i < CT + CA + CV; i += 64)
    s_pool[w][i] = p.pool[(size_t)b * POOLW + i];
  __syncthreads();  // only block-level barrier (covers s_q)

  // ---- modality projections + LN + ReLU ----
  {
    float acc = p.text_b[lane];
    for (int i = 0; i < CT; ++i) acc += s_pool[w][i] * p.text_w[i * D + lane];
    float mu = wsum(acc) * (1.f / D);
    float d = acc - mu;
    float var = wsum(d * d) * (1.f / D);
    s_z[w][0 * D + lane] =
        fmaxf(d * rsqrtf(var + 1e-5f) * p.text_ln_g[lane] + p.text_ln_b[lane], 0.f);

    acc = p.audio_b[lane];
    for (int i = 0; i < CA; ++i) acc += s_pool[w][CT + i] * p.audio_w[i * D + lane];
    mu = wsum(acc) * (1.f / D); d = acc - mu; var = wsum(d * d) * (1.f / D);
    s_z[w][1 * D + lane] =
        fmaxf(d * rsqrtf(var + 1e-5f) * p.audio_ln_g[lane] + p.audio_ln_b[lane], 0.f);

    acc = p.video_b[lane];
    for (int i = 0; i < CV; ++i) acc += s_pool[w][CT + CA + i] * p.video_w[i * D + lane];
    mu = wsum(acc) * (1.f / D); d = acc - mu; var = wsum(d * d) * (1.f / D);
    s_z[w][2 * D + lane] =
        fmaxf(d * rsqrtf(var + 1e-5f) * p.video_ln_g[lane] + p.video_ln_b[lane], 0.f);
  }
  WB();

  // ---- k, v projections (v stays in registers: lane j only ever needs v[s][j]) ----
  float vreg[3];
#pragma unroll
  for (int s = 0; s < 3; ++s) {
    float ak = p.bk[lane], av = p.bv[lane];
    for (int i = 0; i < D; ++i) {
      float z = s_z[w][s * D + i];
      ak += z * p.wk[i * D + lane];
      av += z * p.wv[i * D + lane];
    }
    s_k[w][s * D + lane] = ak;
    vreg[s] = av;
  }
  WB();

  // ---- scores (16-lane-group dot over head dim) + softmax over s, per lane's head ----
  float aw[L_][3];
#pragma unroll
  for (int l = 0; l < L_; ++l) {
    float sc0 = hsum16(s_q[l * D + lane] * s_k[w][0 * D + lane]) * 0.25f;
    float sc1 = hsum16(s_q[l * D + lane] * s_k[w][1 * D + lane]) * 0.25f;
    float sc2 = hsum16(s_q[l * D + lane] * s_k[w][2 * D + lane]) * 0.25f;
    float mx = fmaxf(sc0, fmaxf(sc1, sc2));
    float e0 = expf(sc0 - mx), e1 = expf(sc1 - mx), e2 = expf(sc2 - mx);
    float inv = 1.f / (e0 + e1 + e2);
    aw[l][0] = e0 * inv; aw[l][1] = e1 * inv; aw[l][2] = e2 * inv;
  }

  // ---- attn @ v ----
#pragma unroll
  for (int l = 0; l < L_; ++l)
    s_ao[w][l * D + lane] = aw[l][0] * vreg[0] + aw[l][1] * vreg[1] + aw[l][2] * vreg[2];
  WB();

  // ---- out-proj + residual + LN1 ----
#pragma unroll
  for (int l = 0; l < L_; ++l) {
    float acc = p.bo[lane];
    for (int i = 0; i < D; ++i) acc += s_ao[w][l * D + i] * p.wo[i * D + lane];
    float x = p.latent[l * D + lane] + acc;
    float mu = wsum(x) * (1.f / D);
    float d = x - mu;
    float var = wsum(d * d) * (1.f / D);
    s_lat1[w][l * D + lane] = d * rsqrtf(var + 1e-5f) * p.n1_g[lane] + p.n1_b[lane];
  }
  WB();

  // ---- FFN1 + exact GELU (lane covers 4 of 256 cols; all 4 latents per i) ----
  {
    float hacc[L_][4];
#pragma unroll
    for (int k = 0; k < 4; ++k) {
      float bb = p.ffn_b1[k * 64 + lane];
#pragma unroll
      for (int l = 0; l < L_; ++l) hacc[l][k] = bb;
    }
    for (int i = 0; i < D; ++i) {
      float x0 = s_lat1[w][0 * D + i], x1 = s_lat1[w][1 * D + i];
      float x2 = s_lat1[w][2 * D + i], x3 = s_lat1[w][3 * D + i];
#pragma unroll
      for (int k = 0; k < 4; ++k) {
        float wv = p.ffn_w1[i * 256 + k * 64 + lane];
        hacc[0][k] += x0 * wv; hacc[1][k] += x1 * wv;
        hacc[2][k] += x2 * wv; hacc[3][k] += x3 * wv;
      }
    }
#pragma unroll
    for (int l = 0; l < L_; ++l)
#pragma unroll
      for (int k = 0; k < 4; ++k) {
        float x = hacc[l][k];
        s_h1[w][l * 256 + k * 64 + lane] = 0.5f * x * (1.f + erff(x * 0.70710678118654752f));
      }
  }
  WB();

  // ---- FFN2 + residual + LN2 -> f ----
  float fl;
  {
    float fsum = 0.f;
#pragma unroll
    for (int l = 0; l < L_; ++l) {
      float acc = p.ffn_b2[lane];
      for (int m2 = 0; m2 < 256; ++m2) acc += s_h1[w][l * 256 + m2] * p.ffn_w2[m2 * D + lane];
      float x = s_lat1[w][l * D + lane] + acc;
      float mu = wsum(x) * (1.f / D);
      float d = x - mu;
      float var = wsum(d * d) * (1.f / D);
      fsum += d * rsqrtf(var + 1e-5f) * p.n2_g[lane] + p.n2_b[lane];
    }
    fl = 0.25f * fsum;
    s_f[w][lane] = fl;
    p.out[(size_t)B_ * 75 + (size_t)b * D + lane] = fl;
  }
  WB();

  // ---- router: hidden + LN + ReLU, logits via wave reductions, softmax in regs ----
  float w0, w1, w2, w3;
  {
    float acc = p.r_b1[lane];
    for (int i = 0; i < D; ++i) acc += s_f[w][i] * p.r_w1[i * D + lane];
    float mu = wsum(acc) * (1.f / D);
    float d = acc - mu;
    float var = wsum(d * d) * (1.f / D);
    float rr = fmaxf(d * rsqrtf(var + 1e-5f) * p.r_ln_g[lane] + p.r_ln_b[lane], 0.f);
    float l0 = wsum(rr * p.r_w2[lane * E_ + 0]) + p.r_b2[0];
    float l1 = wsum(rr * p.r_w2[lane * E_ + 1]) + p.r_b2[1];
    float l2 = wsum(rr * p.r_w2[lane * E_ + 2]) + p.r_b2[2];
    float l3 = wsum(rr * p.r_w2[lane * E_ + 3]) + p.r_b2[3];
    float mx = fmaxf(fmaxf(l0, l1), fmaxf(l2, l3));
    float e0 = expf(l0 - mx), e1 = expf(l1 - mx), e2 = expf(l2 - mx), e3 = expf(l3 - mx);
    float inv = 1.f / (e0 + e1 + e2 + e3);
    w0 = e0 * inv; w1 = e1 * inv; w2 = e2 * inv; w3 = e3 * inv;
    float wsel = (lane == 0) ? w0 : (lane == 1) ? w1 : (lane == 2) ? w2 : w3;
    if (lane < E_) p.out[(size_t)B_ * 7 + (size_t)b * E_ + lane] = wsel;
  }

  // ---- views: lanes 0-31 -> view1, lanes 32-63 -> view2 ----
  {
    const float* PW = (lane < 32) ? p.p1_w : p.p2_w;
    const float* PB = (lane < 32) ? p.p1_b : p.p2_b;
    const int col = lane & 31;
    float acc = PB[col];
    for (int i = 0; i < D; ++i) acc += s_f[w][i] * PW[i * 32 + col];
    const size_t base = (lane < 32) ? (size_t)B_ * 139 : (size_t)B_ * 171;
    p.out[base + (size_t)b * 32 + col] = acc;
  }

  // ---- LoRA down (lanes 0-31: e = lane/8, r = lane%8) ----
  if (lane < E_ * R_) {
    const int e = lane >> 3, r = lane & 7;
    float acc = 0.f;
    for (int dd = 0; dd < D; ++dd) acc += s_f[w][dd] * p.lora_down[e * D * R_ + dd * R_ + r];
    s_down[w][lane] = acc;
  }
  WB();

  // ---- LoRA up + expert mix -> fused ----
  float fused;
  {
    const float we4[4] = {w0, w1, w2, w3};
    float acc = 0.f;
#pragma unroll
    for (int e = 0; e < E_; ++e) {
      float up = 0.f;
#pragma unroll
      for (int r = 0; r < R_; ++r)
        up += s_down[w][e * R_ + r] * p.lora_up[e * R_ * D + r * D + lane];
      acc += we4[e] * (fl + 2.0f * up);  // SCALING = 16/8 = 2
    }
    fused = acc;
    p.out[(size_t)B_ * 11 + (size_t)b * D + lane] = fused;
  }

  // ---- classifier ----
  {
    float mu = wsum(fused) * (1.f / D);
    float d = fused - mu;
    float var = wsum(d * d) * (1.f / D);
    s_cl[w][lane] = d * rsqrtf(var + 1e-5f) * p.c_ln_g[lane] + p.c_ln_b[lane];
  }
  WB();
  {
    float acc = p.c_b1[lane];
    for (int i = 0; i < D; ++i) acc += s_cl[w][i] * p.c_w1[i * D + lane];
    float h = fmaxf(acc, 0.f);
#pragma unroll
    for (int nc = 0; nc < NC; ++nc) {
      float lg = wsum(h * p.c_w2[lane * NC + nc]) + p.c_b2[nc];
      if (lane == nc) p.out[(size_t)b * NC + nc] = lg;
    }
  }
}

extern "C" void kernel_launch(void* const* d_in, const int* in_sizes, int n_in,
                              void* d_out, int out_size, void* d_ws, size_t ws_size,
                              hipStream_t stream) {
  (void)in_sizes; (void)n_in; (void)out_size; (void)ws_size;
  Params p;
  memcpy(&p, d_in, 50 * sizeof(void*));  // 50 const pointers in setup_inputs() order
  p.out = (float*)d_out;
  // workspace layout: pooled [B_, POOLW] f32 (3.41 MB) then q [L_*D] f32 (1 KB)
  float* pool = (float*)d_ws;
  float* qbuf = pool + (size_t)B_ * POOLW;
  p.pool = pool;
  p.qbuf = qbuf;
  pool_kernel<<<dim3(B_, 3), dim3(256), 0, stream>>>(p.text, p.audio, p.video,
                                                     p.latent, p.wq, p.bq, pool, qbuf);
  head_kernel<<<dim3(B_ / 4), dim3(256), 0, stream>>>(p);
}

// Round 2
// 698.899 us; speedup vs baseline: 1.7749x; 1.0229x over previous
//
#include <hip/hip_runtime.h>
#include <math.h>
#include <string.h>

#define B_   2048
#define TT   128
#define TA   256
#define TV   256
#define CT   300
#define CA   74
#define CV   35
#define D    64
#define E_   4
#define R_   8
#define H_   4
#define L_   4
#define NC   7
#define POOLW 416  // 409 padded to 16B multiple

// All INPUTS are float32 (reference dtype; confirmed: bf16 reads gave NaN in R1 of prior session).
// OUTPUT buffer is float32. Params = 50 const pointers in setup_inputs() order, then out.
struct Params {
  const float *text, *audio, *video;
  const float *text_w, *text_b, *text_ln_g, *text_ln_b;
  const float *audio_w, *audio_b, *audio_ln_g, *audio_ln_b;
  const float *video_w, *video_b, *video_ln_g, *video_ln_b;
  const float *latent;
  const float *wq, *bq, *wk, *bk, *wv, *bv, *wo, *bo;
  const float *n1_g, *n1_b, *ffn_w1, *ffn_b1, *ffn_w2, *ffn_b2, *n2_g, *n2_b;
  const float *r_w1, *r_b1, *r_ln_g, *r_ln_b, *r_w2, *r_b2;
  const float *p1_w, *p1_b, *p2_w, *p2_b;
  const float *lora_down, *lora_up;
  const float *c_ln_g, *c_ln_b, *c_w1, *c_b1, *c_w2, *c_b2;
  float *out;
};

// sum across the 64 lanes of a wave (all lanes get the result)
__device__ __forceinline__ float wsum(float v) {
#pragma unroll
  for (int m = 32; m >= 1; m >>= 1) v += __shfl_xor(v, m, 64);
  return v;
}
// sum within each 16-lane group (all lanes of the group get the result)
__device__ __forceinline__ float hsum16(float v) {
#pragma unroll
  for (int m = 8; m >= 1; m >>= 1) v += __shfl_xor(v, m, 64);
  return v;
}
// compile-time reorder fence for wave-synchronous LDS produce->consume (R1-verified pattern)
#define WB() __builtin_amdgcn_wave_barrier()

// ============ Fused kernel: one block = 4 samples; pool (block-coop) then head (per-wave) ============
// Grid 512 x 256thr -> 2 blocks/CU. Pool phase of some blocks overlaps head phase of others,
// so the 543 MB HBM stream and the latency-bound head chains overlap instead of serializing.
__global__ __launch_bounds__(256) void fused_kernel(Params p) {
  const int tid = threadIdx.x;
  const int lane = tid & 63;
  const int w = tid >> 6;
  const int b0 = blockIdx.x * 4;
  const int b = b0 + w;

  // pooling scratch (dead after reduce phase)
  __shared__ __align__(16) float4 sbufT[3][4][75];  // 14.4 KB
  __shared__ __align__(8)  float2 sbufA[6][4][37];  //  7.1 KB
  __shared__ float sbufV[7][4][35];                 //  3.9 KB
  // block-shared / per-wave state
  __shared__ __align__(16) float s_pool[4][POOLW];
  __shared__ float s_q[L_ * D];
  __shared__ float s_z[4][3 * D];
  __shared__ float s_k[4][3 * D];
  __shared__ float s_ao[4][L_ * D];
  __shared__ float s_lat1[4][L_ * D];
  __shared__ float s_h1w[4][256];   // per-latent staging (saves 3 KB/wave vs full h1)
  __shared__ float s_f[4][D];
  __shared__ float s_down[4][E_ * R_];
  __shared__ float s_cl[4][D];

  // ---------------- phase 1: issue ALL pooling loads for 4 samples (no barriers) ----------------
  {  // text: rows stride 1200B (16B aligned); 75 f4-cols x 3 row-groups
    const int c4 = tid % 75, g = tid / 75;
    if (g < 3) {
      float4 acc[4];
#pragma unroll
      for (int s = 0; s < 4; ++s) acc[s] = make_float4(0.f, 0.f, 0.f, 0.f);
      for (int t = g; t < TT; t += 3) {
#pragma unroll
        for (int s = 0; s < 4; ++s) {
          float4 v = *reinterpret_cast<const float4*>(
              p.text + (size_t)(b0 + s) * (TT * CT) + t * CT + 4 * c4);
          acc[s].x += v.x; acc[s].y += v.y; acc[s].z += v.z; acc[s].w += v.w;
        }
      }
#pragma unroll
      for (int s = 0; s < 4; ++s) sbufT[g][s][c4] = acc[s];
    }
  }
  {  // audio: rows stride 296B (8B aligned); 37 f2-cols x 6 row-groups
    const int c2 = tid % 37, g = tid / 37;
    if (g < 6) {
      float2 acc[4];
#pragma unroll
      for (int s = 0; s < 4; ++s) acc[s] = make_float2(0.f, 0.f);
      for (int t = g; t < TA; t += 6) {
#pragma unroll
        for (int s = 0; s < 4; ++s) {
          float2 v = *reinterpret_cast<const float2*>(
              p.audio + (size_t)(b0 + s) * (TA * CA) + t * CA + 2 * c2);
          acc[s].x += v.x; acc[s].y += v.y;
        }
      }
#pragma unroll
      for (int s = 0; s < 4; ++s) sbufA[g][s][c2] = acc[s];
    }
  }
  {  // video: scalar; 35 cols x 7 row-groups
    const int c = tid % 35, g = tid / 35;
    if (g < 7) {
      float acc[4] = {0.f, 0.f, 0.f, 0.f};
      for (int t = g; t < TV; t += 7) {
#pragma unroll
        for (int s = 0; s < 4; ++s)
          acc[s] += p.video[(size_t)(b0 + s) * (TV * CV) + t * CV + c];
      }
#pragma unroll
      for (int s = 0; s < 4; ++s) sbufV[g][s][c] = acc[s];
    }
  }
  {  // q = latent @ wq + bq (b-independent, per block): tid = l*64 + j
    const int l = tid >> 6, j = tid & 63;
    float acc = p.bq[j];
    for (int i = 0; i < D; ++i) acc += p.latent[l * D + i] * p.wq[i * D + j];
    s_q[tid] = acc;
  }
  __syncthreads();

  // ---------------- reduce partials for all 4 samples in parallel ----------------
  if (tid < 75) {
#pragma unroll
    for (int s = 0; s < 4; ++s) {
      float4 a = sbufT[0][s][tid], bb = sbufT[1][s][tid], c = sbufT[2][s][tid];
      float4 r;
      r.x = (a.x + bb.x + c.x) * (1.f / TT);
      r.y = (a.y + bb.y + c.y) * (1.f / TT);
      r.z = (a.z + bb.z + c.z) * (1.f / TT);
      r.w = (a.w + bb.w + c.w) * (1.f / TT);
      *reinterpret_cast<float4*>(&s_pool[s][4 * tid]) = r;
    }
  } else if (tid < 112) {
    const int c2 = tid - 75;
#pragma unroll
    for (int s = 0; s < 4; ++s) {
      float2 r = make_float2(0.f, 0.f);
#pragma unroll
      for (int g = 0; g < 6; ++g) { float2 v = sbufA[g][s][c2]; r.x += v.x; r.y += v.y; }
      r.x *= (1.f / TA); r.y *= (1.f / TA);
      *reinterpret_cast<float2*>(&s_pool[s][CT + 2 * c2]) = r;
    }
  } else if (tid < 147) {
    const int c = tid - 112;
#pragma unroll
    for (int s = 0; s < 4; ++s) {
      float r = 0.f;
#pragma unroll
      for (int g = 0; g < 7; ++g) r += sbufV[g][s][c];
      s_pool[s][CT + CA + c] = r * (1.f / TV);
    }
  }
  __syncthreads();  // last block barrier; head phase is wave-independent below

  // ---------------- phase 2: head, one wave per sample (identical math to R1) ----------------
  // ---- modality projections + LN + ReLU ----
  {
    float acc = p.text_b[lane];
    for (int i = 0; i < CT; ++i) acc += s_pool[w][i] * p.text_w[i * D + lane];
    float mu = wsum(acc) * (1.f / D);
    float d = acc - mu;
    float var = wsum(d * d) * (1.f / D);
    s_z[w][0 * D + lane] =
        fmaxf(d * rsqrtf(var + 1e-5f) * p.text_ln_g[lane] + p.text_ln_b[lane], 0.f);

    acc = p.audio_b[lane];
    for (int i = 0; i < CA; ++i) acc += s_pool[w][CT + i] * p.audio_w[i * D + lane];
    mu = wsum(acc) * (1.f / D); d = acc - mu; var = wsum(d * d) * (1.f / D);
    s_z[w][1 * D + lane] =
        fmaxf(d * rsqrtf(var + 1e-5f) * p.audio_ln_g[lane] + p.audio_ln_b[lane], 0.f);

    acc = p.video_b[lane];
    for (int i = 0; i < CV; ++i) acc += s_pool[w][CT + CA + i] * p.video_w[i * D + lane];
    mu = wsum(acc) * (1.f / D); d = acc - mu; var = wsum(d * d) * (1.f / D);
    s_z[w][2 * D + lane] =
        fmaxf(d * rsqrtf(var + 1e-5f) * p.video_ln_g[lane] + p.video_ln_b[lane], 0.f);
  }
  WB();

  // ---- k, v projections (v stays in registers) ----
  float vreg[3];
#pragma unroll
  for (int s = 0; s < 3; ++s) {
    float ak = p.bk[lane], av = p.bv[lane];
    for (int i = 0; i < D; ++i) {
      float z = s_z[w][s * D + i];
      ak += z * p.wk[i * D + lane];
      av += z * p.wv[i * D + lane];
    }
    s_k[w][s * D + lane] = ak;
    vreg[s] = av;
  }
  WB();

  // ---- scores (16-lane-group dot per head) + softmax over s ----
  float aw[L_][3];
#pragma unroll
  for (int l = 0; l < L_; ++l) {
    float sc0 = hsum16(s_q[l * D + lane] * s_k[w][0 * D + lane]) * 0.25f;
    float sc1 = hsum16(s_q[l * D + lane] * s_k[w][1 * D + lane]) * 0.25f;
    float sc2 = hsum16(s_q[l * D + lane] * s_k[w][2 * D + lane]) * 0.25f;
    float mx = fmaxf(sc0, fmaxf(sc1, sc2));
    float e0 = expf(sc0 - mx), e1 = expf(sc1 - mx), e2 = expf(sc2 - mx);
    float inv = 1.f / (e0 + e1 + e2);
    aw[l][0] = e0 * inv; aw[l][1] = e1 * inv; aw[l][2] = e2 * inv;
  }

  // ---- attn @ v ----
#pragma unroll
  for (int l = 0; l < L_; ++l)
    s_ao[w][l * D + lane] = aw[l][0] * vreg[0] + aw[l][1] * vreg[1] + aw[l][2] * vreg[2];
  WB();

  // ---- out-proj + residual + LN1 ----
#pragma unroll
  for (int l = 0; l < L_; ++l) {
    float acc = p.bo[lane];
    for (int i = 0; i < D; ++i) acc += s_ao[w][l * D + i] * p.wo[i * D + lane];
    float x = p.latent[l * D + lane] + acc;
    float mu = wsum(x) * (1.f / D);
    float d = x - mu;
    float var = wsum(d * d) * (1.f / D);
    s_lat1[w][l * D + lane] = d * rsqrtf(var + 1e-5f) * p.n1_g[lane] + p.n1_b[lane];
  }
  WB();

  // ---- FFN1 (all 16 accumulators in regs) ----
  float hacc[L_][4];
  {
#pragma unroll
    for (int k = 0; k < 4; ++k) {
      float bb = p.ffn_b1[k * 64 + lane];
#pragma unroll
      for (int l = 0; l < L_; ++l) hacc[l][k] = bb;
    }
    for (int i = 0; i < D; ++i) {
      float x0 = s_lat1[w][0 * D + i], x1 = s_lat1[w][1 * D + i];
      float x2 = s_lat1[w][2 * D + i], x3 = s_lat1[w][3 * D + i];
#pragma unroll
      for (int k = 0; k < 4; ++k) {
        float wv = p.ffn_w1[i * 256 + k * 64 + lane];
        hacc[0][k] += x0 * wv; hacc[1][k] += x1 * wv;
        hacc[2][k] += x2 * wv; hacc[3][k] += x3 * wv;
      }
    }
  }

  // ---- GELU + FFN2 + residual + LN2 -> f, staged per-latent through 256-float buffer ----
  float fl;
  {
    float fsum = 0.f;
#pragma unroll
    for (int l = 0; l < L_; ++l) {
#pragma unroll
      for (int k = 0; k < 4; ++k) {
        float x = hacc[l][k];
        s_h1w[w][k * 64 + lane] = 0.5f * x * (1.f + erff(x * 0.70710678118654752f));
      }
      WB();
      float acc = p.ffn_b2[lane];
      for (int m2 = 0; m2 < 256; ++m2) acc += s_h1w[w][m2] * p.ffn_w2[m2 * D + lane];
      float x = s_lat1[w][l * D + lane] + acc;
      float mu = wsum(x) * (1.f / D);
      float d = x - mu;
      float var = wsum(d * d) * (1.f / D);
      fsum += d * rsqrtf(var + 1e-5f) * p.n2_g[lane] + p.n2_b[lane];
      WB();
    }
    fl = 0.25f * fsum;
    s_f[w][lane] = fl;
    p.out[(size_t)B_ * 75 + (size_t)b * D + lane] = fl;
  }
  WB();

  // ---- router: hidden + LN + ReLU, logits via wave reductions, softmax in regs ----
  float w0, w1, w2, w3;
  {
    float acc = p.r_b1[lane];
    for (int i = 0; i < D; ++i) acc += s_f[w][i] * p.r_w1[i * D + lane];
    float mu = wsum(acc) * (1.f / D);
    float d = acc - mu;
    float var = wsum(d * d) * (1.f / D);
    float rr = fmaxf(d * rsqrtf(var + 1e-5f) * p.r_ln_g[lane] + p.r_ln_b[lane], 0.f);
    float l0 = wsum(rr * p.r_w2[lane * E_ + 0]) + p.r_b2[0];
    float l1 = wsum(rr * p.r_w2[lane * E_ + 1]) + p.r_b2[1];
    float l2 = wsum(rr * p.r_w2[lane * E_ + 2]) + p.r_b2[2];
    float l3 = wsum(rr * p.r_w2[lane * E_ + 3]) + p.r_b2[3];
    float mx = fmaxf(fmaxf(l0, l1), fmaxf(l2, l3));
    float e0 = expf(l0 - mx), e1 = expf(l1 - mx), e2 = expf(l2 - mx), e3 = expf(l3 - mx);
    float inv = 1.f / (e0 + e1 + e2 + e3);
    w0 = e0 * inv; w1 = e1 * inv; w2 = e2 * inv; w3 = e3 * inv;
    float wsel = (lane == 0) ? w0 : (lane == 1) ? w1 : (lane == 2) ? w2 : w3;
    if (lane < E_) p.out[(size_t)B_ * 7 + (size_t)b * E_ + lane] = wsel;
  }

  // ---- views: lanes 0-31 -> view1, lanes 32-63 -> view2 ----
  {
    const float* PW = (lane < 32) ? p.p1_w : p.p2_w;
    const float* PB = (lane < 32) ? p.p1_b : p.p2_b;
    const int col = lane & 31;
    float acc = PB[col];
    for (int i = 0; i < D; ++i) acc += s_f[w][i] * PW[i * 32 + col];
    const size_t base = (lane < 32) ? (size_t)B_ * 139 : (size_t)B_ * 171;
    p.out[base + (size_t)b * 32 + col] = acc;
  }

  // ---- LoRA down (lanes 0-31: e = lane/8, r = lane%8) ----
  if (lane < E_ * R_) {
    const int e = lane >> 3, r = lane & 7;
    float acc = 0.f;
    for (int dd = 0; dd < D; ++dd) acc += s_f[w][dd] * p.lora_down[e * D * R_ + dd * R_ + r];
    s_down[w][lane] = acc;
  }
  WB();

  // ---- LoRA up + expert mix -> fused ----
  float fused;
  {
    const float we4[4] = {w0, w1, w2, w3};
    float acc = 0.f;
#pragma unroll
    for (int e = 0; e < E_; ++e) {
      float up = 0.f;
#pragma unroll
      for (int r = 0; r < R_; ++r)
        up += s_down[w][e * R_ + r] * p.lora_up[e * R_ * D + r * D + lane];
      acc += we4[e] * (fl + 2.0f * up);  // SCALING = 16/8 = 2
    }
    fused = acc;
    p.out[(size_t)B_ * 11 + (size_t)b * D + lane] = fused;
  }

  // ---- classifier ----
  {
    float mu = wsum(fused) * (1.f / D);
    float d = fused - mu;
    float var = wsum(d * d) * (1.f / D);
    s_cl[w][lane] = d * rsqrtf(var + 1e-5f) * p.c_ln_g[lane] + p.c_ln_b[lane];
  }
  WB();
  {
    float acc = p.c_b1[lane];
    for (int i = 0; i < D; ++i) acc += s_cl[w][i] * p.c_w1[i * D + lane];
    float h = fmaxf(acc, 0.f);
#pragma unroll
    for (int nc = 0; nc < NC; ++nc) {
      float lg = wsum(h * p.c_w2[lane * NC + nc]) + p.c_b2[nc];
      if (lane == nc) p.out[(size_t)b * NC + nc] = lg;
    }
  }
}

extern "C" void kernel_launch(void* const* d_in, const int* in_sizes, int n_in,
                              void* d_out, int out_size, void* d_ws, size_t ws_size,
                              hipStream_t stream) {
  (void)in_sizes; (void)n_in; (void)out_size; (void)d_ws; (void)ws_size;
  Params p;
  memcpy(&p, d_in, 50 * sizeof(void*));  // 50 const pointers in setup_inputs() order
  p.out = (float*)d_out;
  fused_kernel<<<dim3(B_ / 4), dim3(256), 0, stream>>>(p);
}